// Round 4
// baseline (768.890 us; speedup 1.0000x reference)
//
#include <hip/hip_runtime.h>
#include <hip/hip_bf16.h>
#include <stdint.h>

#define N_BANK 131072
#define B_ROWS 256
#define DIM 2048
#define HID 512
#define CAND_CAP 1024
#define WIN 64
#define Z_THRESH 2.5528f

typedef __attribute__((ext_vector_type(8))) short bf16x8;
typedef __attribute__((ext_vector_type(8))) unsigned short ushort8;
typedef __attribute__((ext_vector_type(4))) float f32x4;

// ---------------- threefry2x32 (exact JAX semantics; verified R1-R3) ----------------
__device__ __forceinline__ void threefry2x32(uint32_t k0, uint32_t k1,
                                             uint32_t x0, uint32_t x1,
                                             uint32_t& o0, uint32_t& o1) {
  uint32_t ks0 = k0, ks1 = k1, ks2 = k0 ^ k1 ^ 0x1BD11BDAu;
  uint32_t ks[3] = {ks0, ks1, ks2};
  x0 += ks0; x1 += ks1;
  const int rotA[4] = {13, 15, 26, 6};
  const int rotB[4] = {17, 29, 16, 24};
  #pragma unroll
  for (int g = 0; g < 5; ++g) {
    const int* rr = (g & 1) ? rotB : rotA;
    #pragma unroll
    for (int i = 0; i < 4; ++i) {
      x0 += x1;
      x1 = (x1 << rr[i]) | (x1 >> (32 - rr[i]));
      x1 ^= x0;
    }
    x0 += ks[(g + 1) % 3];
    x1 += ks[(g + 2) % 3] + (uint32_t)(g + 1);
  }
  o0 = x0; o1 = x1;
}

__device__ __forceinline__ void jax_split(uint32_t k0, uint32_t k1,
                                          uint32_t& a0, uint32_t& a1,
                                          uint32_t& b0, uint32_t& b1) {
  uint32_t o00, o10, o01, o11;
  threefry2x32(k0, k1, 0u, 2u, o00, o10);
  threefry2x32(k0, k1, 1u, 3u, o01, o11);
  a0 = o00; a1 = o01;
  b0 = o10; b1 = o11;
}

__device__ __forceinline__ ushort f2bf(float f) {
  uint32_t u = __float_as_uint(f);
  return (ushort)((u + 0x7FFFu + ((u >> 16) & 1u)) >> 16);  // RNE
}

// hw packed f32->bf16 (rounding mode need not match f2bf: bf16 sims only gate
// the candidate window; final picks come from the fp64 rerank)
__device__ __forceinline__ uint32_t cvt_pk(float lo, float hi) {
  uint32_t d;
  asm("v_cvt_pk_bf16_f32 %0, %1, %2" : "=v"(d) : "v"(lo), "v"(hi));
  return d;
}

__device__ __forceinline__ ushort8 cvt8(float4 a, float4 b) {
  union { uint32_t u[4]; ushort8 v; } r;
  r.u[0] = cvt_pk(a.x, a.y);
  r.u[1] = cvt_pk(a.z, a.w);
  r.u[2] = cvt_pk(b.x, b.y);
  r.u[3] = cvt_pk(b.z, b.w);
  return r.v;
}

__device__ __forceinline__ void async16(const void* g, void* l) {
  __builtin_amdgcn_global_load_lds((const __attribute__((address_space(1))) void*)g,
                                   (__attribute__((address_space(3))) void*)l, 16, 0, 0);
}

// ---------------- prep: norm + thr + bf16 convert (pre-swizzled) + zero atomics ----------------
// Abf_s layout: [row][kt][chunk]; chunk c (16B = 8 bf16) holds logical elems
// kt*64 + (c ^ (row&7))*8 .. +8  (XOR involution; Rule 21 source-side).
__global__ __launch_bounds__(256) void prep_kernel(const float* __restrict__ inputs,
                                                   ushort* __restrict__ Abf_s,
                                                   float* __restrict__ invn,
                                                   float* __restrict__ thr,
                                                   int* __restrict__ cand_cnt,
                                                   unsigned long long* __restrict__ pos_comb) {
  int r = blockIdx.x, t = threadIdx.x;
  const float* src = inputs + (size_t)r * DIM + t * 8;
  float4 v0 = *(const float4*)(src);
  float4 v1 = *(const float4*)(src + 4);
  double s = (double)v0.x * v0.x + (double)v0.y * v0.y + (double)v0.z * v0.z + (double)v0.w * v0.w
           + (double)v1.x * v1.x + (double)v1.y * v1.y + (double)v1.z * v1.z + (double)v1.w * v1.w;
  ushort8 c = { f2bf(v0.x), f2bf(v0.y), f2bf(v0.z), f2bf(v0.w),
                f2bf(v1.x), f2bf(v1.y), f2bf(v1.z), f2bf(v1.w) };
  int kt = t >> 3;
  int cl = t & 7;
  int cp = cl ^ (r & 7);
  *(ushort8*)(Abf_s + (size_t)r * DIM + kt * 64 + cp * 8) = c;
  __shared__ double red[256];
  red[t] = s;
  __syncthreads();
  for (int st = 128; st; st >>= 1) {
    if (t < st) red[t] += red[t + st];
    __syncthreads();
  }
  if (t == 0) {
    float nrm = sqrtf((float)red[0]);
    invn[r] = 1.0f / nrm;
    thr[r] = Z_THRESH * nrm;
    cand_cnt[r] = 0;
    pos_comb[r] = 0ull;
  }
}

// ---------------- positive pick: N-parallel scan + atomicMax (verified R2/R3) ----------------
__global__ __launch_bounds__(256) void pos_scan(const int* __restrict__ labels,
                                                const int* __restrict__ targets,
                                                unsigned long long* __restrict__ pos_comb) {
  __shared__ int targ_s[256];
  int tid = threadIdx.x;
  targ_s[tid] = targets[tid];
  __syncthreads();
  int n = blockIdx.x * 256 + tid;
  int c = labels[n];
  uint32_t kn0, kn1, kp0, kp1;
  jax_split(0u, 42u, kn0, kn1, kp0, kp1);
  for (int r = 0; r < 256; ++r) {
    if (targ_s[r] == c) {
      uint32_t i = (uint32_t)r * (uint32_t)N_BANK + (uint32_t)n;
      uint32_t o0, o1, bits;
      if (i < (1u << 24)) { threefry2x32(kp0, kp1, i, i + (1u << 24), o0, o1); bits = o0; }
      else                { threefry2x32(kp0, kp1, i - (1u << 24), i, o0, o1); bits = o1; }
      unsigned long long comb =
          ((unsigned long long)((bits >> 9) + 1u) << 32) | (unsigned long long)(131071u - (uint32_t)n);
      atomicMax(&pos_comb[r], comb);
    }
  }
}

// ---------------- bf16 MFMA GEMM + fused select; double-buffered 2-phase ----------------
// BM=256 (full M: F read exactly once), BN=64, BK=64. A via global_load_lds
// (linear dest, pre-swizzled source); F reg-staged, hw cvt, swizzled ds_write.
// LDS 80KB -> 2 blocks/CU; one barrier per K-step; next tile's loads in
// flight across the MFMA block (T3-lite minimum 2-phase recipe).
__global__ __launch_bounds__(256, 2) void gemm_select(
    const ushort* __restrict__ Abf_s, const float* __restrict__ F,
    const float* __restrict__ thr, const int* __restrict__ labels,
    const int* __restrict__ targets, float* __restrict__ cand_val,
    int* __restrict__ cand_idx, int* __restrict__ cand_cnt) {
  __shared__ ushort As[2][256 * 64];   // 64KB: [row][chunk^(row&7)]
  __shared__ ushort Bs[2][64 * 64];    // 16KB: [row][chunk^(row&7)]
  const int tid = threadIdx.x;
  const int bn = blockIdx.x * 64;
  const int wid = tid >> 6;
  const int lane = tid & 63;
  const int lr = lane & 15;
  const int lk = lane >> 4;

  // F staging: thread covers row=tid>>2, 16 k-elems (2 chunks) at fq=tid&3
  const int frow = tid >> 2;
  const int fq = tid & 3;
  const float* fptr = F + (size_t)(bn + frow) * DIM + fq * 16;
  const int fr7 = frow & 7;
  const int bo0 = frow * 64 + ((fq * 2) ^ fr7) * 8;
  const int bo1 = frow * 64 + ((fq * 2 + 1) ^ fr7) * 8;

  // A async staging: issue j covers rows (wid*8+j)*8..+8, lane->16B chunk
  const int arow_off = lane >> 3;
  const int achk = lane & 7;

  f32x4 acc[4][4];
  #pragma unroll
  for (int i = 0; i < 4; ++i)
    #pragma unroll
    for (int j = 0; j < 4; ++j) acc[i][j] = (f32x4){0.f, 0.f, 0.f, 0.f};

  // prologue: stage tile 0 into buffer 0
  {
    float4 f0 = *(const float4*)(fptr);
    float4 f1 = *(const float4*)(fptr + 4);
    float4 f2 = *(const float4*)(fptr + 8);
    float4 f3 = *(const float4*)(fptr + 12);
    #pragma unroll
    for (int j = 0; j < 8; ++j) {
      int row = (wid * 8 + j) * 8 + arow_off;
      async16(Abf_s + (size_t)row * DIM + achk * 8, &As[0][(wid * 8 + j) * 512]);
    }
    *(ushort8*)(&Bs[0][bo0]) = cvt8(f0, f1);
    *(ushort8*)(&Bs[0][bo1]) = cvt8(f2, f3);
  }
  __syncthreads();

  for (int kt = 0; kt < 32; ++kt) {
    const int cur = kt & 1;
    const int nxt = cur ^ 1;
    float4 f0, f1, f2, f3;
    if (kt < 31) {
      // F reg-loads FIRST (their vmcnt wait later leaves the asyncs in flight)
      const float* fp2 = fptr + (kt + 1) * 64;
      f0 = *(const float4*)(fp2);
      f1 = *(const float4*)(fp2 + 4);
      f2 = *(const float4*)(fp2 + 8);
      f3 = *(const float4*)(fp2 + 12);
      #pragma unroll
      for (int j = 0; j < 8; ++j) {
        int row = (wid * 8 + j) * 8 + arow_off;
        async16(Abf_s + (size_t)row * DIM + (kt + 1) * 64 + achk * 8,
                &As[nxt][(wid * 8 + j) * 512]);
      }
    }
    // compute on buf[cur] — covers the in-flight loads
    #pragma unroll
    for (int kk = 0; kk < 2; ++kk) {
      bf16x8 af[4], bfv[4];
      #pragma unroll
      for (int fi = 0; fi < 4; ++fi) {
        int row_a = wid * 64 + fi * 16 + lr;
        af[fi] = *(const bf16x8*)(&As[cur][row_a * 64 + (((kk * 4 + lk) ^ (lr & 7)) * 8)]);
      }
      #pragma unroll
      for (int fj = 0; fj < 4; ++fj) {
        int row_b = fj * 16 + lr;
        bfv[fj] = *(const bf16x8*)(&Bs[cur][row_b * 64 + (((kk * 4 + lk) ^ (lr & 7)) * 8)]);
      }
      #pragma unroll
      for (int fi = 0; fi < 4; ++fi)
        #pragma unroll
        for (int fj = 0; fj < 4; ++fj)
          acc[fi][fj] = __builtin_amdgcn_mfma_f32_16x16x32_bf16(af[fi], bfv[fj], acc[fi][fj], 0, 0, 0);
    }
    if (kt < 31) {
      *(ushort8*)(&Bs[nxt][bo0]) = cvt8(f0, f1);
      *(ushort8*)(&Bs[nxt][bo1]) = cvt8(f2, f3);
    }
    __syncthreads();
  }

  // fused threshold selection (S never hits memory)
  int lb[4];
  #pragma unroll
  for (int fj = 0; fj < 4; ++fj) lb[fj] = labels[bn + fj * 16 + lr];
  #pragma unroll
  for (int fi = 0; fi < 4; ++fi) {
    #pragma unroll
    for (int reg = 0; reg < 4; ++reg) {
      int row = wid * 64 + fi * 16 + lk * 4 + reg;  // C/D: col=lane&15, row=(lane>>4)*4+reg
      float tr = thr[row];
      int tg = targets[row];
      #pragma unroll
      for (int fj = 0; fj < 4; ++fj) {
        float v = acc[fi][fj][reg];
        if (v > tr && lb[fj] != tg) {
          int p = atomicAdd(&cand_cnt[row], 1);
          if (p < CAND_CAP) {
            cand_val[row * CAND_CAP + p] = v;
            cand_idx[row * CAND_CAP + p] = bn + fj * 16 + lr;
          }
        }
      }
    }
  }
}

// ---------------- windowed exact fp64 re-rank (+ inline neg_pick; verified R3) ----------------
__global__ __launch_bounds__(512) void rerank(const float* __restrict__ inputs,
                                              const float* __restrict__ F,
                                              const float* __restrict__ cand_val,
                                              const int* __restrict__ cand_idx,
                                              const int* __restrict__ cand_cnt,
                                              int* __restrict__ neg_sel) {
  int r = blockIdx.x;
  int tid = threadIdx.x;
  int m = cand_cnt[r]; if (m > CAND_CAP) m = CAND_CAP;
  __shared__ float vals[CAND_CAP];
  __shared__ int idxs[CAND_CAP];
  __shared__ float xr[DIM];
  __shared__ int wlist[WIN];
  __shared__ double dvals[WIN];
  __shared__ int wcnt, s_pick;
  if (tid == 0) {
    wcnt = 0; neg_sel[r] = 0;
    uint32_t kn0, kn1, kp0, kp1, k10, k11, k20, k21, o0, o1, hi, lo;
    jax_split(0u, 42u, kn0, kn1, kp0, kp1);
    jax_split(kn0, kn1, k10, k11, k20, k21);
    if (r < 128) { threefry2x32(k10, k11, (uint32_t)r, (uint32_t)(r + 128), o0, o1); hi = o0; }
    else         { threefry2x32(k10, k11, (uint32_t)(r - 128), (uint32_t)r, o0, o1); hi = o1; }
    if (r < 128) { threefry2x32(k20, k21, (uint32_t)r, (uint32_t)(r + 128), o0, o1); lo = o0; }
    else         { threefry2x32(k20, k21, (uint32_t)(r - 128), (uint32_t)r, o0, o1); lo = o1; }
    s_pick = (int)(((hi % 500u) * 296u + (lo % 500u)) % 500u);
  }
  for (int d = tid; d < DIM; d += 512) xr[d] = inputs[(size_t)r * DIM + d];
  for (int c = tid; c < m; c += 512) {
    vals[c] = cand_val[r * CAND_CAP + c];
    idxs[c] = cand_idx[r * CAND_CAP + c];
  }
  __syncthreads();
  int pick = s_pick;
  int lo = pick - 32; if (lo < 0) lo = 0;
  int hi = pick + 32; if (hi > m) hi = m;
  for (int c = tid; c < m; c += 512) {
    float v = vals[c]; int id = idxs[c]; int rk = 0;
    for (int j = 0; j < m; ++j) {
      float vj = vals[j];
      rk += (vj > v) || (vj == v && idxs[j] < id);
    }
    if (rk >= lo && rk < hi) { int p = atomicAdd(&wcnt, 1); if (p < WIN) wlist[p] = c; }
  }
  __syncthreads();
  int wn = wcnt; if (wn > WIN) wn = WIN;
  int wave = tid >> 6, lane = tid & 63;
  for (int w = wave; w < wn; w += 8) {
    const float* f = F + (size_t)idxs[wlist[w]] * DIM;
    double s = 0.0;
    for (int d = lane; d < DIM; d += 64) s += (double)xr[d] * (double)f[d];
    for (int off = 32; off; off >>= 1) s += __shfl_down(s, off);
    if (lane == 0) dvals[w] = s;
  }
  __syncthreads();
  if (tid < wn) {
    double v = dvals[tid]; int id = idxs[wlist[tid]]; int rk = lo;
    for (int j = 0; j < wn; ++j) {
      double vj = dvals[j];
      rk += (vj > v) || (vj == v && idxs[wlist[j]] < id);
    }
    if (rk == pick) neg_sel[r] = id;
  }
}

// ---------------- siamese head: one block does pos+neg (verified R3) ----------------
__global__ __launch_bounds__(256) void head_kernel(const float* __restrict__ inputs,
                                                   const float* __restrict__ F,
                                                   const float* __restrict__ invn,
                                                   const unsigned long long* __restrict__ pos_comb,
                                                   const int* __restrict__ neg_sel,
                                                   const float* __restrict__ W1,
                                                   const float* __restrict__ b1,
                                                   const float* __restrict__ W2,
                                                   const float* __restrict__ b2,
                                                   float* __restrict__ terms) {
  int r = blockIdx.x;
  unsigned long long pc = pos_comb[r];
  int sp = pc ? (int)(131071u - (uint32_t)(pc & 0xffffffffull)) : 0;
  int sn = neg_sel[r];
  __shared__ float zp[DIM];
  __shared__ float zn[DIM];
  __shared__ float2 red[256];
  float inv = invn[r];
  const float* xr = inputs + (size_t)r * DIM;
  const float* fp = F + (size_t)sp * DIM;
  const float* fn = F + (size_t)sn * DIM;
  for (int d = threadIdx.x; d < DIM; d += 256) {
    float x = xr[d] * inv;
    zp[d] = fabsf(x - fp[d]);
    zn[d] = fabsf(x - fn[d]);
  }
  __syncthreads();
  int j = threadIdx.x;
  float ap0 = 0.f, ap1 = 0.f, an0 = 0.f, an1 = 0.f;
  for (int d = 0; d < DIM; ++d) {
    float w0 = W1[(size_t)d * HID + j];
    float w1 = W1[(size_t)d * HID + j + 256];
    float zpd = zp[d], znd = zn[d];
    ap0 = fmaf(zpd, w0, ap0); ap1 = fmaf(zpd, w1, ap1);
    an0 = fmaf(znd, w0, an0); an1 = fmaf(znd, w1, an1);
  }
  float bj0 = b1[j], bj1 = b1[j + 256];
  float w20 = W2[j], w21 = W2[j + 256];
  ap0 += bj0; ap1 += bj1; an0 += bj0; an1 += bj1;
  float hp0 = ap0 >= 0.f ? ap0 : 0.01f * ap0;
  float hp1 = ap1 >= 0.f ? ap1 : 0.01f * ap1;
  float hn0 = an0 >= 0.f ? an0 : 0.01f * an0;
  float hn1 = an1 >= 0.f ? an1 : 0.01f * an1;
  red[j] = make_float2(hp0 * w20 + hp1 * w21, hn0 * w20 + hn1 * w21);
  __syncthreads();
  for (int st = 128; st; st >>= 1) {
    if (j < st) {
      red[j].x += red[j + st].x;
      red[j].y += red[j + st].y;
    }
    __syncthreads();
  }
  if (j == 0) {
    float lp = red[0].x + b2[0];
    float ln = red[0].y + b2[0];
    float xp = -lp;
    float sp_t = fmaxf(xp, 0.f) + log1pf(expf(-fabsf(xp)));
    float sn_t = fmaxf(ln, 0.f) + log1pf(expf(-fabsf(ln)));
    terms[2 * r] = sp_t * (1.0f / 256.0f);
    terms[2 * r + 1] = sn_t * (1.0f / 256.0f);
  }
}

__global__ __launch_bounds__(512) void final_reduce(const float* __restrict__ terms,
                                                    float* __restrict__ out) {
  __shared__ float red[512];
  int t = threadIdx.x;
  red[t] = terms[t];
  __syncthreads();
  for (int st = 256; st; st >>= 1) {
    if (t < st) red[t] += red[t + st];
    __syncthreads();
  }
  if (t == 0) out[0] = red[0];
}

// ---------------- launch ----------------
extern "C" void kernel_launch(void* const* d_in, const int* in_sizes, int n_in,
                              void* d_out, int out_size, void* d_ws, size_t ws_size,
                              hipStream_t stream) {
  (void)in_sizes; (void)n_in; (void)out_size; (void)ws_size;
  const float* inputs = (const float*)d_in[0];
  const int* targets  = (const int*)d_in[1];
  const float* F      = (const float*)d_in[2];
  const int* labels   = (const int*)d_in[3];
  const float* W1     = (const float*)d_in[4];
  const float* b1     = (const float*)d_in[5];
  const float* W2     = (const float*)d_in[6];
  const float* b2     = (const float*)d_in[7];
  float* out = (float*)d_out;

  char* ws = (char*)d_ws;
  size_t off = 0;
  ushort* Abf_s   = (ushort*)(ws + off); off += (size_t)B_ROWS * DIM * 2;        // 1 MB
  float* cand_val = (float*)(ws + off); off += (size_t)B_ROWS * CAND_CAP * 4;    // 1 MB
  int* cand_idx   = (int*)(ws + off);   off += (size_t)B_ROWS * CAND_CAP * 4;    // 1 MB
  int* cand_cnt   = (int*)(ws + off);   off += 1024;
  unsigned long long* pos_comb = (unsigned long long*)(ws + off); off += 2048;
  int* neg_sel    = (int*)(ws + off);   off += 1024;
  float* invn     = (float*)(ws + off); off += 1024;
  float* thr      = (float*)(ws + off); off += 1024;
  float* terms    = (float*)(ws + off); off += 2048;

  prep_kernel<<<B_ROWS, 256, 0, stream>>>(inputs, Abf_s, invn, thr, cand_cnt, pos_comb);
  pos_scan<<<N_BANK / 256, 256, 0, stream>>>(labels, targets, pos_comb);
  gemm_select<<<N_BANK / 64, 256, 0, stream>>>(Abf_s, F, thr, labels, targets,
                                               cand_val, cand_idx, cand_cnt);
  rerank<<<B_ROWS, 512, 0, stream>>>(inputs, F, cand_val, cand_idx, cand_cnt, neg_sel);
  head_kernel<<<B_ROWS, 256, 0, stream>>>(inputs, F, invn, pos_comb, neg_sel,
                                          W1, b1, W2, b2, terms);
  final_reduce<<<1, 512, 0, stream>>>(terms, out);
}

// Round 5
// 661.510 us; speedup vs baseline: 1.1623x; 1.1623x over previous
//
#include <hip/hip_runtime.h>
#include <hip/hip_bf16.h>
#include <stdint.h>

#define N_BANK 131072
#define B_ROWS 256
#define DIM 2048
#define HID 512
#define CAND_CAP 1024
#define WIN 64
#define Z_THRESH 2.5528f

typedef __attribute__((ext_vector_type(8))) short bf16x8;
typedef __attribute__((ext_vector_type(8))) unsigned short ushort8;
typedef __attribute__((ext_vector_type(4))) float f32x4;

// ---------------- threefry2x32 (exact JAX semantics; verified R1-R4) ----------------
__device__ __forceinline__ void threefry2x32(uint32_t k0, uint32_t k1,
                                             uint32_t x0, uint32_t x1,
                                             uint32_t& o0, uint32_t& o1) {
  uint32_t ks0 = k0, ks1 = k1, ks2 = k0 ^ k1 ^ 0x1BD11BDAu;
  uint32_t ks[3] = {ks0, ks1, ks2};
  x0 += ks0; x1 += ks1;
  const int rotA[4] = {13, 15, 26, 6};
  const int rotB[4] = {17, 29, 16, 24};
  #pragma unroll
  for (int g = 0; g < 5; ++g) {
    const int* rr = (g & 1) ? rotB : rotA;
    #pragma unroll
    for (int i = 0; i < 4; ++i) {
      x0 += x1;
      x1 = (x1 << rr[i]) | (x1 >> (32 - rr[i]));
      x1 ^= x0;
    }
    x0 += ks[(g + 1) % 3];
    x1 += ks[(g + 2) % 3] + (uint32_t)(g + 1);
  }
  o0 = x0; o1 = x1;
}

__device__ __forceinline__ void jax_split(uint32_t k0, uint32_t k1,
                                          uint32_t& a0, uint32_t& a1,
                                          uint32_t& b0, uint32_t& b1) {
  uint32_t o00, o10, o01, o11;
  threefry2x32(k0, k1, 0u, 2u, o00, o10);
  threefry2x32(k0, k1, 1u, 3u, o01, o11);
  a0 = o00; a1 = o01;
  b0 = o10; b1 = o11;
}

__device__ __forceinline__ ushort f2bf(float f) {
  uint32_t u = __float_as_uint(f);
  return (ushort)((u + 0x7FFFu + ((u >> 16) & 1u)) >> 16);  // RNE
}

// hw packed f32->bf16 (rounding mode need not match f2bf: bf16 sims only gate
// the candidate window; final picks come from the fp64 rerank)
__device__ __forceinline__ uint32_t cvt_pk(float lo, float hi) {
  uint32_t d;
  asm("v_cvt_pk_bf16_f32 %0, %1, %2" : "=v"(d) : "v"(lo), "v"(hi));
  return d;
}

__device__ __forceinline__ ushort8 cvt8(float4 a, float4 b) {
  union { uint32_t u[4]; ushort8 v; } r;
  r.u[0] = cvt_pk(a.x, a.y);
  r.u[1] = cvt_pk(a.z, a.w);
  r.u[2] = cvt_pk(b.x, b.y);
  r.u[3] = cvt_pk(b.z, b.w);
  return r.v;
}

// ---------------- prep: norm + thr + A->bf16 in MFMA-fragment order ----------------
// Abf chunk layout (16B chunks): chunk = kt*2048 + wid*512 + kk*256 + fi*64 + lane
// where row = wid*64 + fi*16 + (lane&15), k = kt*64 + kk*32 + (lane>>4)*8 .. +8.
// Each wave's fragment load is then 64 consecutive 16B chunks (1KB coalesced).
__global__ __launch_bounds__(256) void prep_kernel(const float* __restrict__ inputs,
                                                   ushort* __restrict__ Abf,
                                                   float* __restrict__ invn,
                                                   float* __restrict__ thr,
                                                   int* __restrict__ cand_cnt,
                                                   unsigned long long* __restrict__ pos_comb) {
  int r = blockIdx.x, t = threadIdx.x;
  const float* src = inputs + (size_t)r * DIM + t * 8;
  float4 v0 = *(const float4*)(src);
  float4 v1 = *(const float4*)(src + 4);
  double s = (double)v0.x * v0.x + (double)v0.y * v0.y + (double)v0.z * v0.z + (double)v0.w * v0.w
           + (double)v1.x * v1.x + (double)v1.y * v1.y + (double)v1.z * v1.z + (double)v1.w * v1.w;
  ushort8 c = { f2bf(v0.x), f2bf(v0.y), f2bf(v0.z), f2bf(v0.w),
                f2bf(v1.x), f2bf(v1.y), f2bf(v1.z), f2bf(v1.w) };
  int kt = t >> 3;
  int kk = (t >> 2) & 1;
  int lk = t & 3;
  int chunk = kt * 2048 + (r >> 6) * 512 + kk * 256 + ((r >> 4) & 3) * 64
            + lk * 16 + (r & 15);
  *(ushort8*)(Abf + (size_t)chunk * 8) = c;
  __shared__ double red[256];
  red[t] = s;
  __syncthreads();
  for (int st = 128; st; st >>= 1) {
    if (t < st) red[t] += red[t + st];
    __syncthreads();
  }
  if (t == 0) {
    float nrm = sqrtf((float)red[0]);
    invn[r] = 1.0f / nrm;
    thr[r] = Z_THRESH * nrm;
    cand_cnt[r] = 0;
    pos_comb[r] = 0ull;
  }
}

// ---------------- positive pick: N-parallel scan + atomicMax (verified R2-R4) ----------------
__global__ __launch_bounds__(256) void pos_scan(const int* __restrict__ labels,
                                                const int* __restrict__ targets,
                                                unsigned long long* __restrict__ pos_comb) {
  __shared__ int targ_s[256];
  int tid = threadIdx.x;
  targ_s[tid] = targets[tid];
  __syncthreads();
  int n = blockIdx.x * 256 + tid;
  int c = labels[n];
  uint32_t kn0, kn1, kp0, kp1;
  jax_split(0u, 42u, kn0, kn1, kp0, kp1);
  for (int r = 0; r < 256; ++r) {
    if (targ_s[r] == c) {
      uint32_t i = (uint32_t)r * (uint32_t)N_BANK + (uint32_t)n;
      uint32_t o0, o1, bits;
      if (i < (1u << 24)) { threefry2x32(kp0, kp1, i, i + (1u << 24), o0, o1); bits = o0; }
      else                { threefry2x32(kp0, kp1, i - (1u << 24), i, o0, o1); bits = o1; }
      unsigned long long comb =
          ((unsigned long long)((bits >> 9) + 1u) << 32) | (unsigned long long)(131071u - (uint32_t)n);
      atomicMax(&pos_comb[r], comb);
    }
  }
}

// ---------------- bf16 MFMA GEMM + fused select ----------------
// BM=256 (full M: F read exactly once), BN=64, BK=64.
// A: per-wave register fragments straight from L2 (fragment-order Abf) --
//    no LDS, no barrier needed (wave stages exactly what it consumes).
// B(F): reg-load -> cvt_pk bf16 -> swizzled LDS, double-buffered; published by
//    raw "lgkmcnt(0); s_barrier" so vmcnt NEVER drains in the loop: next
//    tile's A/F loads stay in flight across the barrier (T4 mechanism).
#define GSTEP(KT, AC, AN, CUR, NXT)                                           \
  {                                                                           \
    if ((KT) < 31) {                                                          \
      const ushort* ab = aptr + ((KT) + 1) * 16384;                           \
      _Pragma("unroll")                                                       \
      for (int q = 0; q < 8; ++q) AN[q] = *(const bf16x8*)(ab + q * 512);     \
      const float* fp2 = fptr + ((KT) + 1) * 64;                              \
      fr0 = *(const float4*)(fp2);                                            \
      fr1 = *(const float4*)(fp2 + 4);                                        \
      fr2 = *(const float4*)(fp2 + 8);                                        \
      fr3 = *(const float4*)(fp2 + 12);                                       \
    }                                                                         \
    _Pragma("unroll")                                                         \
    for (int kk = 0; kk < 2; ++kk) {                                          \
      bf16x8 bfv[4];                                                          \
      _Pragma("unroll")                                                       \
      for (int fj = 0; fj < 4; ++fj) {                                        \
        int row_b = fj * 16 + lr;                                             \
        bfv[fj] = *(const bf16x8*)(&Bs[CUR][row_b * 64 +                      \
                        (((kk * 4 + lk) ^ (lr & 7)) * 8)]);                   \
      }                                                                       \
      _Pragma("unroll")                                                       \
      for (int fi = 0; fi < 4; ++fi) {                                        \
        _Pragma("unroll")                                                     \
        for (int fj = 0; fj < 4; ++fj)                                        \
          acc[fi][fj] = __builtin_amdgcn_mfma_f32_16x16x32_bf16(              \
              AC[kk * 4 + fi], bfv[fj], acc[fi][fj], 0, 0, 0);                \
      }                                                                       \
    }                                                                         \
    if ((KT) < 31) {                                                          \
      *(ushort8*)(&Bs[NXT][bo0]) = cvt8(fr0, fr1);                            \
      *(ushort8*)(&Bs[NXT][bo1]) = cvt8(fr2, fr3);                            \
      asm volatile("s_waitcnt lgkmcnt(0)\n\ts_barrier" ::: "memory");         \
    }                                                                         \
  }

__global__ __launch_bounds__(256, 2) void gemm_select(
    const ushort* __restrict__ Abf, const float* __restrict__ F,
    const float* __restrict__ thr, const int* __restrict__ labels,
    const int* __restrict__ targets, float* __restrict__ cand_val,
    int* __restrict__ cand_idx, int* __restrict__ cand_cnt) {
  __shared__ ushort Bs[2][64 * 64];    // 16KB total: [row][chunk^(row&7)]
  const int tid = threadIdx.x;
  const int bn = blockIdx.x * 64;
  const int wid = tid >> 6;
  const int lane = tid & 63;
  const int lr = lane & 15;
  const int lk = lane >> 4;

  // F staging: thread covers row=tid>>2, 16 k-elems (2 chunks) at fq=tid&3
  const int frow = tid >> 2;
  const int fq = tid & 3;
  const float* fptr = F + (size_t)(bn + frow) * DIM + fq * 16;
  const int fr7 = frow & 7;
  const int bo0 = frow * 64 + ((fq * 2) ^ fr7) * 8;
  const int bo1 = frow * 64 + ((fq * 2 + 1) ^ fr7) * 8;

  // A fragment base: wave-private, fragment-order global layout
  const ushort* aptr = Abf + (size_t)(wid * 512 + lane) * 8;

  f32x4 acc[4][4];
  #pragma unroll
  for (int i = 0; i < 4; ++i)
    #pragma unroll
    for (int j = 0; j < 4; ++j) acc[i][j] = (f32x4){0.f, 0.f, 0.f, 0.f};

  bf16x8 A0[8], A1[8];
  float4 fr0, fr1, fr2, fr3;

  // prologue: tile 0
  #pragma unroll
  for (int q = 0; q < 8; ++q) A0[q] = *(const bf16x8*)(aptr + q * 512);
  fr0 = *(const float4*)(fptr);
  fr1 = *(const float4*)(fptr + 4);
  fr2 = *(const float4*)(fptr + 8);
  fr3 = *(const float4*)(fptr + 12);
  *(ushort8*)(&Bs[0][bo0]) = cvt8(fr0, fr1);
  *(ushort8*)(&Bs[0][bo1]) = cvt8(fr2, fr3);
  asm volatile("s_waitcnt lgkmcnt(0)\n\ts_barrier" ::: "memory");

  for (int k2 = 0; k2 < 16; ++k2) {
    int kt0 = 2 * k2;
    GSTEP(kt0, A0, A1, 0, 1);
    GSTEP((kt0 + 1), A1, A0, 1, 0);
  }

  // fused threshold selection (S never hits memory)
  int lb[4];
  #pragma unroll
  for (int fj = 0; fj < 4; ++fj) lb[fj] = labels[bn + fj * 16 + lr];
  #pragma unroll
  for (int fi = 0; fi < 4; ++fi) {
    #pragma unroll
    for (int reg = 0; reg < 4; ++reg) {
      int row = wid * 64 + fi * 16 + lk * 4 + reg;  // C/D: col=lane&15, row=(lane>>4)*4+reg
      float tr = thr[row];
      int tg = targets[row];
      #pragma unroll
      for (int fj = 0; fj < 4; ++fj) {
        float v = acc[fi][fj][reg];
        if (v > tr && lb[fj] != tg) {
          int p = atomicAdd(&cand_cnt[row], 1);
          if (p < CAND_CAP) {
            cand_val[row * CAND_CAP + p] = v;
            cand_idx[row * CAND_CAP + p] = bn + fj * 16 + lr;
          }
        }
      }
    }
  }
}

// ---------------- windowed exact fp64 re-rank (+ inline neg_pick; verified R3/R4) ----------------
__global__ __launch_bounds__(512) void rerank(const float* __restrict__ inputs,
                                              const float* __restrict__ F,
                                              const float* __restrict__ cand_val,
                                              const int* __restrict__ cand_idx,
                                              const int* __restrict__ cand_cnt,
                                              int* __restrict__ neg_sel) {
  int r = blockIdx.x;
  int tid = threadIdx.x;
  int m = cand_cnt[r]; if (m > CAND_CAP) m = CAND_CAP;
  __shared__ float vals[CAND_CAP];
  __shared__ int idxs[CAND_CAP];
  __shared__ float xr[DIM];
  __shared__ int wlist[WIN];
  __shared__ double dvals[WIN];
  __shared__ int wcnt, s_pick;
  if (tid == 0) {
    wcnt = 0; neg_sel[r] = 0;
    uint32_t kn0, kn1, kp0, kp1, k10, k11, k20, k21, o0, o1, hi, lo;
    jax_split(0u, 42u, kn0, kn1, kp0, kp1);
    jax_split(kn0, kn1, k10, k11, k20, k21);
    if (r < 128) { threefry2x32(k10, k11, (uint32_t)r, (uint32_t)(r + 128), o0, o1); hi = o0; }
    else         { threefry2x32(k10, k11, (uint32_t)(r - 128), (uint32_t)r, o0, o1); hi = o1; }
    if (r < 128) { threefry2x32(k20, k21, (uint32_t)r, (uint32_t)(r + 128), o0, o1); lo = o0; }
    else         { threefry2x32(k20, k21, (uint32_t)(r - 128), (uint32_t)r, o0, o1); lo = o1; }
    s_pick = (int)(((hi % 500u) * 296u + (lo % 500u)) % 500u);
  }
  for (int d = tid; d < DIM; d += 512) xr[d] = inputs[(size_t)r * DIM + d];
  for (int c = tid; c < m; c += 512) {
    vals[c] = cand_val[r * CAND_CAP + c];
    idxs[c] = cand_idx[r * CAND_CAP + c];
  }
  __syncthreads();
  int pick = s_pick;
  int lo = pick - 32; if (lo < 0) lo = 0;
  int hi = pick + 32; if (hi > m) hi = m;
  for (int c = tid; c < m; c += 512) {
    float v = vals[c]; int id = idxs[c]; int rk = 0;
    for (int j = 0; j < m; ++j) {
      float vj = vals[j];
      rk += (vj > v) || (vj == v && idxs[j] < id);
    }
    if (rk >= lo && rk < hi) { int p = atomicAdd(&wcnt, 1); if (p < WIN) wlist[p] = c; }
  }
  __syncthreads();
  int wn = wcnt; if (wn > WIN) wn = WIN;
  int wave = tid >> 6, lane = tid & 63;
  for (int w = wave; w < wn; w += 8) {
    const float* f = F + (size_t)idxs[wlist[w]] * DIM;
    double s = 0.0;
    for (int d = lane; d < DIM; d += 64) s += (double)xr[d] * (double)f[d];
    for (int off = 32; off; off >>= 1) s += __shfl_down(s, off);
    if (lane == 0) dvals[w] = s;
  }
  __syncthreads();
  if (tid < wn) {
    double v = dvals[tid]; int id = idxs[wlist[tid]]; int rk = lo;
    for (int j = 0; j < wn; ++j) {
      double vj = dvals[j];
      rk += (vj > v) || (vj == v && idxs[wlist[j]] < id);
    }
    if (rk == pick) neg_sel[r] = id;
  }
}

// ---------------- siamese head: one block does pos+neg (verified R3/R4) ----------------
__global__ __launch_bounds__(256) void head_kernel(const float* __restrict__ inputs,
                                                   const float* __restrict__ F,
                                                   const float* __restrict__ invn,
                                                   const unsigned long long* __restrict__ pos_comb,
                                                   const int* __restrict__ neg_sel,
                                                   const float* __restrict__ W1,
                                                   const float* __restrict__ b1,
                                                   const float* __restrict__ W2,
                                                   const float* __restrict__ b2,
                                                   float* __restrict__ terms) {
  int r = blockIdx.x;
  unsigned long long pc = pos_comb[r];
  int sp = pc ? (int)(131071u - (uint32_t)(pc & 0xffffffffull)) : 0;
  int sn = neg_sel[r];
  __shared__ float zp[DIM];
  __shared__ float zn[DIM];
  __shared__ float2 red[256];
  float inv = invn[r];
  const float* xr = inputs + (size_t)r * DIM;
  const float* fp = F + (size_t)sp * DIM;
  const float* fn = F + (size_t)sn * DIM;
  for (int d = threadIdx.x; d < DIM; d += 256) {
    float x = xr[d] * inv;
    zp[d] = fabsf(x - fp[d]);
    zn[d] = fabsf(x - fn[d]);
  }
  __syncthreads();
  int j = threadIdx.x;
  float ap0 = 0.f, ap1 = 0.f, an0 = 0.f, an1 = 0.f;
  for (int d = 0; d < DIM; ++d) {
    float w0 = W1[(size_t)d * HID + j];
    float w1 = W1[(size_t)d * HID + j + 256];
    float zpd = zp[d], znd = zn[d];
    ap0 = fmaf(zpd, w0, ap0); ap1 = fmaf(zpd, w1, ap1);
    an0 = fmaf(znd, w0, an0); an1 = fmaf(znd, w1, an1);
  }
  float bj0 = b1[j], bj1 = b1[j + 256];
  float w20 = W2[j], w21 = W2[j + 256];
  ap0 += bj0; ap1 += bj1; an0 += bj0; an1 += bj1;
  float hp0 = ap0 >= 0.f ? ap0 : 0.01f * ap0;
  float hp1 = ap1 >= 0.f ? ap1 : 0.01f * ap1;
  float hn0 = an0 >= 0.f ? an0 : 0.01f * an0;
  float hn1 = an1 >= 0.f ? an1 : 0.01f * an1;
  red[j] = make_float2(hp0 * w20 + hp1 * w21, hn0 * w20 + hn1 * w21);
  __syncthreads();
  for (int st = 128; st; st >>= 1) {
    if (j < st) {
      red[j].x += red[j + st].x;
      red[j].y += red[j + st].y;
    }
    __syncthreads();
  }
  if (j == 0) {
    float lp = red[0].x + b2[0];
    float ln = red[0].y + b2[0];
    float xp = -lp;
    float sp_t = fmaxf(xp, 0.f) + log1pf(expf(-fabsf(xp)));
    float sn_t = fmaxf(ln, 0.f) + log1pf(expf(-fabsf(ln)));
    terms[2 * r] = sp_t * (1.0f / 256.0f);
    terms[2 * r + 1] = sn_t * (1.0f / 256.0f);
  }
}

__global__ __launch_bounds__(512) void final_reduce(const float* __restrict__ terms,
                                                    float* __restrict__ out) {
  __shared__ float red[512];
  int t = threadIdx.x;
  red[t] = terms[t];
  __syncthreads();
  for (int st = 256; st; st >>= 1) {
    if (t < st) red[t] += red[t + st];
    __syncthreads();
  }
  if (t == 0) out[0] = red[0];
}

// ---------------- launch ----------------
extern "C" void kernel_launch(void* const* d_in, const int* in_sizes, int n_in,
                              void* d_out, int out_size, void* d_ws, size_t ws_size,
                              hipStream_t stream) {
  (void)in_sizes; (void)n_in; (void)out_size; (void)ws_size;
  const float* inputs = (const float*)d_in[0];
  const int* targets  = (const int*)d_in[1];
  const float* F      = (const float*)d_in[2];
  const int* labels   = (const int*)d_in[3];
  const float* W1     = (const float*)d_in[4];
  const float* b1     = (const float*)d_in[5];
  const float* W2     = (const float*)d_in[6];
  const float* b2     = (const float*)d_in[7];
  float* out = (float*)d_out;

  char* ws = (char*)d_ws;
  size_t off = 0;
  ushort* Abf     = (ushort*)(ws + off); off += (size_t)B_ROWS * DIM * 2;        // 1 MB
  float* cand_val = (float*)(ws + off); off += (size_t)B_ROWS * CAND_CAP * 4;    // 1 MB
  int* cand_idx   = (int*)(ws + off);   off += (size_t)B_ROWS * CAND_CAP * 4;    // 1 MB
  int* cand_cnt   = (int*)(ws + off);   off += 1024;
  unsigned long long* pos_comb = (unsigned long long*)(ws + off); off += 2048;
  int* neg_sel    = (int*)(ws + off);   off += 1024;
  float* invn     = (float*)(ws + off); off += 1024;
  float* thr      = (float*)(ws + off); off += 1024;
  float* terms    = (float*)(ws + off); off += 2048;

  prep_kernel<<<B_ROWS, 256, 0, stream>>>(inputs, Abf, invn, thr, cand_cnt, pos_comb);
  pos_scan<<<N_BANK / 256, 256, 0, stream>>>(labels, targets, pos_comb);
  gemm_select<<<N_BANK / 64, 256, 0, stream>>>(Abf, F, thr, labels, targets,
                                               cand_val, cand_idx, cand_cnt);
  rerank<<<B_ROWS, 512, 0, stream>>>(inputs, F, cand_val, cand_idx, cand_cnt, neg_sel);
  head_kernel<<<B_ROWS, 256, 0, stream>>>(inputs, F, invn, pos_comb, neg_sel,
                                          W1, b1, W2, b2, terms);
  final_reduce<<<1, 512, 0, stream>>>(terms, out);
}